// Round 9
// baseline (183.744 us; speedup 1.0000x reference)
//
#include <hip/hip_runtime.h>
#include <hip/hip_bf16.h>

// MHA: B=4, N=1024, E=1024, H=16, d=64.  fp32 I/O, bf16 MFMA internals.
//
// Round 8b: fix __exp2f -> __builtin_amdgcn_exp2f (v_exp_f32 = 2^x on gfx950).
// (1) attn 32 q/wave (128 q/block, 32 MFMA per barrier-pair); (2) exp2-softmax
// with log2(e) folded into Q at the qkv epilogue; (3) gemm_out 64x64 tile.
//
// XOR-swizzled [row][64] LDS tiles: LDS[row][c8] holds G[row][c8 ^ (row&7)];
// frag readers XOR with l15&7.  Staging via global_load_lds(16B).
//
// ws (40 MB fast path): [Qw 8M][Kw 8M][Vw 8M][xb/Ow 8M][Wqb][Wkb][Wvb][Wob]
// (2 MB each).  ws_size < 40 MB -> fp32-W fallback (deterministic branch).
//
// MFMA m89/m91 layouts: A-frag A[m=l&15][k=(l>>4)*8+j]; B-frag same addressing
// from row-major [n][k]; C/D col=l&15, row=(l>>4)*4+reg.

typedef __bf16 bf16x8 __attribute__((ext_vector_type(8)));
typedef __bf16 bf16x4 __attribute__((ext_vector_type(4)));
typedef float  f32x4  __attribute__((ext_vector_type(4)));

#define LOG2E 1.44269504f

__device__ __forceinline__ void glds16(const __bf16* g, __bf16* l) {
  __builtin_amdgcn_global_load_lds(
      (const __attribute__((address_space(1))) void*)g,
      (__attribute__((address_space(3))) void*)l, 16, 0, 0);
}

__global__ __launch_bounds__(256) void cvt_f32_bf16(const float* __restrict__ in,
                                                    __bf16* __restrict__ out, int n4) {
  int i = blockIdx.x * 256 + threadIdx.x;
  if (i < n4) {
    float4 v = *(const float4*)(in + (size_t)i * 4);
    bf16x4 b = {(__bf16)v.x, (__bf16)v.y, (__bf16)v.z, (__bf16)v.w};
    *(bf16x4*)(out + (size_t)i * 4) = b;
  }
}

// Fused conversion: x (1M float4) + Wq/Wk/Wv/Wo (256K float4 each).
__global__ __launch_bounds__(256) void cvt_all(const float* __restrict__ x,
                                               const float* __restrict__ Wq,
                                               const float* __restrict__ Wk,
                                               const float* __restrict__ Wv,
                                               const float* __restrict__ Wo,
                                               __bf16* __restrict__ xb,
                                               __bf16* __restrict__ Wqb,
                                               __bf16* __restrict__ Wkb,
                                               __bf16* __restrict__ Wvb,
                                               __bf16* __restrict__ Wob) {
  const int i = blockIdx.x * 256 + threadIdx.x;  // 0..2097151
  const float* src;
  __bf16* dst;
  int off;
  if (i < 1048576) {
    src = x; dst = xb; off = i;
  } else {
    const int j = i - 1048576;
    const int seg = j >> 18;  // 0..3
    off = j & 262143;
    src = (seg == 0) ? Wq : (seg == 1) ? Wk : (seg == 2) ? Wv : Wo;
    dst = (seg == 0) ? Wqb : (seg == 1) ? Wkb : (seg == 2) ? Wvb : Wob;
  }
  float4 v = *(const float4*)(src + (size_t)off * 4);
  bf16x4 b = {(__bf16)v.x, (__bf16)v.y, (__bf16)v.z, (__bf16)v.w};
  *(bf16x4*)(dst + (size_t)off * 4) = b;
}

// ---------------------------------------------------------------------------
// Fused QKV projection, 64x128 tile, BK=64, grid (8,64,3)=1536.
// z=0/1/2 -> Q/K (head layout [b,h,n,d]), V (transposed [b,h,d,n]).
// Q epilogue scaled by log2(e) so attn can use exp2 directly.
// ---------------------------------------------------------------------------
template <bool WBF16>
__global__ __launch_bounds__(256) void gemm_qkv(const __bf16* __restrict__ A,
                                                const void* __restrict__ Wqp,
                                                const void* __restrict__ Wkp,
                                                const void* __restrict__ Wvp,
                                                const float* __restrict__ bq,
                                                const float* __restrict__ bk,
                                                const float* __restrict__ bv,
                                                __bf16* __restrict__ Qw,
                                                __bf16* __restrict__ Kw,
                                                __bf16* __restrict__ Vw) {
  constexpr int BST = WBF16 ? 64 : 72;
  __shared__ __attribute__((aligned(16))) __bf16 As[64][64];
  __shared__ __attribute__((aligned(16))) __bf16 Bs[128 * BST];

  const int tid = threadIdx.x;
  const int lane = tid & 63, w = tid >> 6;
  const int wm = w >> 1, wn = w & 1;
  const int l15 = lane & 15, lq = lane >> 4;
  const int lr = lane >> 3, lc = lane & 7;
  const int xs = l15 & 7;
  const int m0 = blockIdx.y * 64, n0 = blockIdx.x * 128;
  const int z = blockIdx.z;

  const void* Wp = (z == 0) ? Wqp : (z == 1) ? Wkp : Wvp;
  const float* bias = (z == 0) ? bq : (z == 1) ? bk : bv;
  __bf16* C = (z == 0) ? Qw : (z == 1) ? Kw : Vw;
  const float scale = (z == 0) ? LOG2E : 1.0f;

  f32x4 acc[2][4] = {};

  for (int k0 = 0; k0 < 1024; k0 += 64) {
#pragma unroll
    for (int i = 0; i < 2; ++i) {
      const int row = w * 16 + i * 8 + lr;
      glds16(A + (size_t)(m0 + row) * 1024 + k0 + ((lc ^ lr) * 8), &As[row][lc * 8]);
    }
    if (WBF16) {
      const __bf16* Wb = (const __bf16*)Wp;
#pragma unroll
      for (int i = 0; i < 4; ++i) {
        const int row = w * 32 + i * 8 + lr;
        glds16(Wb + (size_t)(n0 + row) * 1024 + k0 + ((lc ^ lr) * 8), &Bs[row * 64 + lc * 8]);
      }
    } else {
      const float* W = (const float*)Wp;
#pragma unroll
      for (int i = 0; i < 8; ++i) {
        const int c = i * 256 + tid, row = c >> 4, col = (c & 15) * 4;
        float4 wv = *(const float4*)(W + (size_t)(n0 + row) * 1024 + k0 + col);
        bf16x4 b4 = {(__bf16)wv.x, (__bf16)wv.y, (__bf16)wv.z, (__bf16)wv.w};
        *(bf16x4*)(&Bs[row * 72 + col]) = b4;
      }
    }
    __syncthreads();
#pragma unroll
    for (int s = 0; s < 2; ++s) {
      bf16x8 af[2], bfv[4];
#pragma unroll
      for (int mt = 0; mt < 2; ++mt)
        af[mt] = *(const bf16x8*)(&As[wm * 32 + mt * 16 + l15][((s * 4 + lq) ^ xs) * 8]);
#pragma unroll
      for (int nt = 0; nt < 4; ++nt) {
        const int row = wn * 64 + nt * 16 + l15;
        if (WBF16)
          bfv[nt] = *(const bf16x8*)(&Bs[row * 64 + (((s * 4 + lq) ^ xs) * 8)]);
        else
          bfv[nt] = *(const bf16x8*)(&Bs[row * 72 + s * 32 + lq * 8]);
      }
#pragma unroll
      for (int mt = 0; mt < 2; ++mt)
#pragma unroll
        for (int nt = 0; nt < 4; ++nt)
          acc[mt][nt] = __builtin_amdgcn_mfma_f32_16x16x32_bf16(
              af[mt], bfv[nt], acc[mt][nt], 0, 0, 0);
    }
    __syncthreads();
  }

#pragma unroll
  for (int mt = 0; mt < 2; ++mt) {
    const int mg_base = m0 + wm * 32 + mt * 16 + lq * 4;
    const int b = mg_base >> 10, nr0 = mg_base & 1023;
#pragma unroll
    for (int nt = 0; nt < 4; ++nt) {
      const int ng = n0 + wn * 64 + nt * 16 + l15;
      const float bv = bias[ng];
      const int h = ng >> 6, dd = ng & 63;
      if (z != 2) {
#pragma unroll
        for (int r = 0; r < 4; ++r) {
          const int mg = mg_base + r;
          const size_t idx =
              ((size_t)(b * 16 + h) << 16) + (size_t)(mg & 1023) * 64 + dd;
          C[idx] = (__bf16)((acc[mt][nt][r] + bv) * scale);
        }
      } else {
        bf16x4 o4 = {(__bf16)(acc[mt][nt][0] + bv), (__bf16)(acc[mt][nt][1] + bv),
                     (__bf16)(acc[mt][nt][2] + bv), (__bf16)(acc[mt][nt][3] + bv)};
        *(bf16x4*)(&C[((size_t)(b * 16 + h) << 16) + (size_t)dd * 1024 + nr0]) = o4;
      }
    }
  }
}

// ---------------------------------------------------------------------------
// Out projection: out[4096,1024] fp32 = O @ Wo^T + bo.  64x64 tile, grid
// (16,64)=1024 blocks (4/CU), 4 waves 2x2 (wave 32x32).  glds+swizzle.
// ---------------------------------------------------------------------------
__global__ __launch_bounds__(256) void gemm_out(const __bf16* __restrict__ A,
                                                const __bf16* __restrict__ W,
                                                const float* __restrict__ bias,
                                                float* __restrict__ C) {
  __shared__ __attribute__((aligned(16))) __bf16 As[64][64];
  __shared__ __attribute__((aligned(16))) __bf16 Bs[64][64];

  const int tid = threadIdx.x;
  const int lane = tid & 63, w = tid >> 6;
  const int wm = w >> 1, wn = w & 1;
  const int l15 = lane & 15, lq = lane >> 4;
  const int lr = lane >> 3, lc = lane & 7;
  const int xs = l15 & 7;
  const int m0 = blockIdx.y * 64, n0 = blockIdx.x * 64;

  f32x4 acc[2][2] = {};

  for (int k0 = 0; k0 < 1024; k0 += 64) {
#pragma unroll
    for (int i = 0; i < 2; ++i) {
      const int row = w * 16 + i * 8 + lr;
      glds16(A + (size_t)(m0 + row) * 1024 + k0 + ((lc ^ lr) * 8), &As[row][lc * 8]);
      glds16(W + (size_t)(n0 + row) * 1024 + k0 + ((lc ^ lr) * 8), &Bs[row][lc * 8]);
    }
    __syncthreads();
#pragma unroll
    for (int s = 0; s < 2; ++s) {
      bf16x8 af[2], bfv[2];
#pragma unroll
      for (int mt = 0; mt < 2; ++mt)
        af[mt] = *(const bf16x8*)(&As[wm * 32 + mt * 16 + l15][((s * 4 + lq) ^ xs) * 8]);
#pragma unroll
      for (int nt = 0; nt < 2; ++nt)
        bfv[nt] = *(const bf16x8*)(&Bs[wn * 32 + nt * 16 + l15][((s * 4 + lq) ^ xs) * 8]);
#pragma unroll
      for (int mt = 0; mt < 2; ++mt)
#pragma unroll
        for (int nt = 0; nt < 2; ++nt)
          acc[mt][nt] = __builtin_amdgcn_mfma_f32_16x16x32_bf16(
              af[mt], bfv[nt], acc[mt][nt], 0, 0, 0);
    }
    __syncthreads();
  }

#pragma unroll
  for (int mt = 0; mt < 2; ++mt) {
    const int mg_base = m0 + wm * 32 + mt * 16 + lq * 4;
#pragma unroll
    for (int nt = 0; nt < 2; ++nt) {
      const int ng = n0 + wn * 32 + nt * 16 + l15;
      const float bv = bias[ng];
#pragma unroll
      for (int r = 0; r < 4; ++r)
        C[(size_t)(mg_base + r) * 1024 + ng] = acc[mt][nt][r] + bv;
    }
  }
}

// ---------------------------------------------------------------------------
// Flash attention, S^T orientation, 32 q per wave (128 q per block).
// Q pre-scaled by log2(e) -> softmax numerator via exp2 (no max shift;
// |logit*log2e| < ~100 << 126, l <= 1024*2^70 safely in fp32 range).
// Per (b,h): Q [n,64], K [n,64], Vt [64,n].  Grid (8, 64).
// Reference divides by sqrt(E)=32 AFTER softmax -> fold into /(l*32).
// ---------------------------------------------------------------------------
__global__ __launch_bounds__(256) void attn_kernel(const __bf16* __restrict__ Q,
                                                   const __bf16* __restrict__ K,
                                                   const __bf16* __restrict__ Vt,
                                                   __bf16* __restrict__ O) {
  __shared__ __attribute__((aligned(16))) __bf16 Qs[128][64];
  __shared__ __attribute__((aligned(16))) __bf16 Ks[64][64];
  __shared__ __attribute__((aligned(16))) __bf16 Vs[64][64];
  __shared__ __attribute__((aligned(16))) __bf16 Ps[4][2][16][72];

  const int tid = threadIdx.x;
  const int lane = tid & 63, w = tid >> 6;
  const int l15 = lane & 15, lq = lane >> 4;
  const int lr = lane >> 3, lc = lane & 7;
  const int xs = l15 & 7;

  const int qt = blockIdx.x;  // 0..7 (128 q per block)
  const int bh = blockIdx.y;  // 0..63
  const __bf16* Qh = Q + (size_t)bh * 65536;
  const __bf16* Kh = K + (size_t)bh * 65536;
  const __bf16* Vh = Vt + (size_t)bh * 65536;

  // stage Q tile (128x64) once via glds, swizzled
#pragma unroll
  for (int i = 0; i < 4; ++i) {
    const int row = w * 32 + i * 8 + lr;
    glds16(Qh + (size_t)(qt * 128 + row) * 64 + ((lc ^ lr) * 8), &Qs[row][lc * 8]);
  }

  float l_run[2] = {0.0f, 0.0f};
  f32x4 oacc[2][4] = {};

  for (int kb = 0; kb < 16; ++kb) {
    __syncthreads();  // prev-iter readers done; also drains Q glds at kb=0
#pragma unroll
    for (int i = 0; i < 2; ++i) {
      const int row = w * 16 + i * 8 + lr;
      glds16(Kh + (size_t)kb * 4096 + (size_t)row * 64 + ((lc ^ lr) * 8), &Ks[row][lc * 8]);
      glds16(Vh + (size_t)row * 1024 + kb * 64 + ((lc ^ lr) * 8), &Vs[row][lc * 8]);
    }
    __syncthreads();

    // S^T: rows = kseq(64), cols = 2 groups of 16 q; K A-frags shared
    f32x4 sacc[2][4] = {};
#pragma unroll
    for (int s = 0; s < 2; ++s) {
      bf16x8 ak[4];
#pragma unroll
      for (int mt = 0; mt < 4; ++mt)
        ak[mt] = *(const bf16x8*)(&Ks[mt * 16 + l15][((s * 4 + lq) ^ xs) * 8]);
#pragma unroll
      for (int g = 0; g < 2; ++g) {
        bf16x8 bq = *(const bf16x8*)(&Qs[w * 32 + g * 16 + l15][((s * 4 + lq) ^ xs) * 8]);
#pragma unroll
        for (int mt = 0; mt < 4; ++mt)
          sacc[g][mt] = __builtin_amdgcn_mfma_f32_16x16x32_bf16(ak[mt], bq, sacc[g][mt], 0, 0, 0);
      }
    }

    // softmax numerator via exp2 (per-lane q = w*32 + g*16 + l15)
#pragma unroll
    for (int g = 0; g < 2; ++g) {
      float sum = 0.0f;
#pragma unroll
      for (int mt = 0; mt < 4; ++mt)
#pragma unroll
        for (int r = 0; r < 4; ++r) {
          const float e = __builtin_amdgcn_exp2f(sacc[g][mt][r]);
          sacc[g][mt][r] = e;
          sum += e;
        }
      sum += __shfl_xor(sum, 16, 64);
      sum += __shfl_xor(sum, 32, 64);
      l_run[g] += sum;
#pragma unroll
      for (int mt = 0; mt < 4; ++mt) {
        bf16x4 p4 = {(__bf16)sacc[g][mt][0], (__bf16)sacc[g][mt][1],
                     (__bf16)sacc[g][mt][2], (__bf16)sacc[g][mt][3]};
        *(bf16x4*)(&Ps[w][g][l15][mt * 16 + lq * 4]) = p4;
      }
    }
    __threadfence_block();  // wave-private P round-trip

    // O^T += Vt · P ; V A-frags shared across groups
#pragma unroll
    for (int s = 0; s < 2; ++s) {
      bf16x8 av[4];
#pragma unroll
      for (int mt = 0; mt < 4; ++mt)
        av[mt] = *(const bf16x8*)(&Vs[mt * 16 + l15][((s * 4 + lq) ^ xs) * 8]);
#pragma unroll
      for (int g = 0; g < 2; ++g) {
        bf16x8 bp = *(const bf16x8*)(&Ps[w][g][l15][s * 32 + lq * 8]);
#pragma unroll
        for (int mt = 0; mt < 4; ++mt)
          oacc[g][mt] = __builtin_amdgcn_mfma_f32_16x16x32_bf16(av[mt], bp, oacc[g][mt], 0, 0, 0);
      }
    }
  }

  // epilogue: O^T col=q(l15), row=d=mt*16+lq*4+r; write O[b*1024+q][h*64+d]
  const int b = bh >> 4, h = bh & 15;
#pragma unroll
  for (int g = 0; g < 2; ++g) {
    const float inv = 1.0f / (l_run[g] * 32.0f);
    const size_t base =
        (size_t)(b * 1024 + qt * 128 + w * 32 + g * 16 + l15) * 1024 + h * 64;
#pragma unroll
    for (int mt = 0; mt < 4; ++mt) {
      bf16x4 o4 = {(__bf16)(oacc[g][mt][0] * inv), (__bf16)(oacc[g][mt][1] * inv),
                   (__bf16)(oacc[g][mt][2] * inv), (__bf16)(oacc[g][mt][3] * inv)};
      *(bf16x4*)(&O[base + mt * 16 + lq * 4]) = o4;
    }
  }
}

// ---------------------------------------------------------------------------
extern "C" void kernel_launch(void* const* d_in, const int* in_sizes, int n_in,
                              void* d_out, int out_size, void* d_ws, size_t ws_size,
                              hipStream_t stream) {
  const float* x  = (const float*)d_in[0];
  const float* Wq = (const float*)d_in[1];
  const float* bq = (const float*)d_in[2];
  const float* Wk = (const float*)d_in[3];
  const float* bk = (const float*)d_in[4];
  const float* Wv = (const float*)d_in[5];
  const float* bv = (const float*)d_in[6];
  const float* Wo = (const float*)d_in[7];
  const float* bo = (const float*)d_in[8];
  float* out = (float*)d_out;

  const size_t SZ = (size_t)4 * 1024 * 1024;  // 4M bf16 per slot (8 MB)
  __bf16* Qw = (__bf16*)d_ws;
  __bf16* Kw = Qw + SZ;
  __bf16* Vw = Kw + SZ;
  __bf16* s3 = Vw + SZ;  // xb during QKV, then Ow
  __bf16* xb = s3;
  __bf16* Ow = s3;

  dim3 blk(256);

  if (ws_size >= (size_t)40 * 1024 * 1024) {
    __bf16* Wqb = s3 + SZ;  // 2 MB each
    __bf16* Wkb = Wqb + SZ / 4;
    __bf16* Wvb = Wkb + SZ / 4;
    __bf16* Wob = Wvb + SZ / 4;
    cvt_all<<<8192, blk, 0, stream>>>(x, Wq, Wk, Wv, Wo, xb, Wqb, Wkb, Wvb, Wob);
    gemm_qkv<true><<<dim3(8, 64, 3), blk, 0, stream>>>(xb, Wqb, Wkb, Wvb,
                                                       bq, bk, bv, Qw, Kw, Vw);
    attn_kernel<<<dim3(8, 64), blk, 0, stream>>>(Qw, Kw, Vw, Ow);
    gemm_out<<<dim3(16, 64), blk, 0, stream>>>(Ow, Wob, bo, out);
  } else {
    __bf16* Wob = Kw;  // Kw dead after attention
    cvt_f32_bf16<<<4096, blk, 0, stream>>>(x, xb, 1048576);
    gemm_qkv<false><<<dim3(8, 64, 3), blk, 0, stream>>>(xb, Wq, Wk, Wv,
                                                        bq, bk, bv, Qw, Kw, Vw);
    attn_kernel<<<dim3(8, 64), blk, 0, stream>>>(Qw, Kw, Vw, Ow);
    cvt_f32_bf16<<<1024, blk, 0, stream>>>(Wo, Wob, 262144);
    gemm_out<<<dim3(16, 64), blk, 0, stream>>>(Ow, Wob, bo, out);
  }
}

// Round 10
// 176.038 us; speedup vs baseline: 1.0438x; 1.0438x over previous
//
#include <hip/hip_runtime.h>
#include <hip/hip_bf16.h>

// MHA: B=4, N=1024, E=1024, H=16, d=64.  fp32 I/O, bf16 MFMA internals.
//
// Round 10: revert attn to 16 q/wave (33 KB LDS, 1024 blocks = 4/CU) — round-8
// 32q variant halved resident blocks (50 KB, 512 blocks = 2/CU) and regressed.
// Keep exp2-softmax (Q pre-scaled by log2(e) in qkv epilogue), keep
// gemm_out 64x64 (4/CU), keep glds+swizzle everywhere.
//
// XOR-swizzled [row][64] LDS tiles: LDS[row][c8] holds G[row][c8 ^ (row&7)];
// frag readers XOR with l15&7.  Staging via global_load_lds(16B).
//
// ws (40 MB fast path): [Qw 8M][Kw 8M][Vw 8M][xb/Ow 8M][Wqb][Wkb][Wvb][Wob]
// (2 MB each).  ws_size < 40 MB -> fp32-W fallback (deterministic branch).
//
// MFMA m89/m91 layouts: A-frag A[m=l&15][k=(l>>4)*8+j]; B-frag same addressing
// from row-major [n][k]; C/D col=l&15, row=(l>>4)*4+reg.

typedef __bf16 bf16x8 __attribute__((ext_vector_type(8)));
typedef __bf16 bf16x4 __attribute__((ext_vector_type(4)));
typedef float  f32x4  __attribute__((ext_vector_type(4)));

#define LOG2E 1.44269504f

__device__ __forceinline__ void glds16(const __bf16* g, __bf16* l) {
  __builtin_amdgcn_global_load_lds(
      (const __attribute__((address_space(1))) void*)g,
      (__attribute__((address_space(3))) void*)l, 16, 0, 0);
}

__global__ __launch_bounds__(256) void cvt_f32_bf16(const float* __restrict__ in,
                                                    __bf16* __restrict__ out, int n4) {
  int i = blockIdx.x * 256 + threadIdx.x;
  if (i < n4) {
    float4 v = *(const float4*)(in + (size_t)i * 4);
    bf16x4 b = {(__bf16)v.x, (__bf16)v.y, (__bf16)v.z, (__bf16)v.w};
    *(bf16x4*)(out + (size_t)i * 4) = b;
  }
}

// Fused conversion: x (1M float4) + Wq/Wk/Wv/Wo (256K float4 each).
__global__ __launch_bounds__(256) void cvt_all(const float* __restrict__ x,
                                               const float* __restrict__ Wq,
                                               const float* __restrict__ Wk,
                                               const float* __restrict__ Wv,
                                               const float* __restrict__ Wo,
                                               __bf16* __restrict__ xb,
                                               __bf16* __restrict__ Wqb,
                                               __bf16* __restrict__ Wkb,
                                               __bf16* __restrict__ Wvb,
                                               __bf16* __restrict__ Wob) {
  const int i = blockIdx.x * 256 + threadIdx.x;  // 0..2097151
  const float* src;
  __bf16* dst;
  int off;
  if (i < 1048576) {
    src = x; dst = xb; off = i;
  } else {
    const int j = i - 1048576;
    const int seg = j >> 18;  // 0..3
    off = j & 262143;
    src = (seg == 0) ? Wq : (seg == 1) ? Wk : (seg == 2) ? Wv : Wo;
    dst = (seg == 0) ? Wqb : (seg == 1) ? Wkb : (seg == 2) ? Wvb : Wob;
  }
  float4 v = *(const float4*)(src + (size_t)off * 4);
  bf16x4 b = {(__bf16)v.x, (__bf16)v.y, (__bf16)v.z, (__bf16)v.w};
  *(bf16x4*)(dst + (size_t)off * 4) = b;
}

// ---------------------------------------------------------------------------
// Fused QKV projection, 64x128 tile, BK=64, grid (8,64,3)=1536 (6 blocks/CU).
// z=0/1/2 -> Q/K (head layout [b,h,n,d]), V (transposed [b,h,d,n]).
// Q epilogue scaled by log2(e) so attn can use exp2 directly.
// ---------------------------------------------------------------------------
template <bool WBF16>
__global__ __launch_bounds__(256) void gemm_qkv(const __bf16* __restrict__ A,
                                                const void* __restrict__ Wqp,
                                                const void* __restrict__ Wkp,
                                                const void* __restrict__ Wvp,
                                                const float* __restrict__ bq,
                                                const float* __restrict__ bk,
                                                const float* __restrict__ bv,
                                                __bf16* __restrict__ Qw,
                                                __bf16* __restrict__ Kw,
                                                __bf16* __restrict__ Vw) {
  constexpr int BST = WBF16 ? 64 : 72;
  __shared__ __attribute__((aligned(16))) __bf16 As[64][64];
  __shared__ __attribute__((aligned(16))) __bf16 Bs[128 * BST];

  const int tid = threadIdx.x;
  const int lane = tid & 63, w = tid >> 6;
  const int wm = w >> 1, wn = w & 1;
  const int l15 = lane & 15, lq = lane >> 4;
  const int lr = lane >> 3, lc = lane & 7;
  const int xs = l15 & 7;
  const int m0 = blockIdx.y * 64, n0 = blockIdx.x * 128;
  const int z = blockIdx.z;

  const void* Wp = (z == 0) ? Wqp : (z == 1) ? Wkp : Wvp;
  const float* bias = (z == 0) ? bq : (z == 1) ? bk : bv;
  __bf16* C = (z == 0) ? Qw : (z == 1) ? Kw : Vw;
  const float scale = (z == 0) ? LOG2E : 1.0f;

  f32x4 acc[2][4] = {};

  for (int k0 = 0; k0 < 1024; k0 += 64) {
#pragma unroll
    for (int i = 0; i < 2; ++i) {
      const int row = w * 16 + i * 8 + lr;
      glds16(A + (size_t)(m0 + row) * 1024 + k0 + ((lc ^ lr) * 8), &As[row][lc * 8]);
    }
    if (WBF16) {
      const __bf16* Wb = (const __bf16*)Wp;
#pragma unroll
      for (int i = 0; i < 4; ++i) {
        const int row = w * 32 + i * 8 + lr;
        glds16(Wb + (size_t)(n0 + row) * 1024 + k0 + ((lc ^ lr) * 8), &Bs[row * 64 + lc * 8]);
      }
    } else {
      const float* W = (const float*)Wp;
#pragma unroll
      for (int i = 0; i < 8; ++i) {
        const int c = i * 256 + tid, row = c >> 4, col = (c & 15) * 4;
        float4 wv = *(const float4*)(W + (size_t)(n0 + row) * 1024 + k0 + col);
        bf16x4 b4 = {(__bf16)wv.x, (__bf16)wv.y, (__bf16)wv.z, (__bf16)wv.w};
        *(bf16x4*)(&Bs[row * 72 + col]) = b4;
      }
    }
    __syncthreads();
#pragma unroll
    for (int s = 0; s < 2; ++s) {
      bf16x8 af[2], bfv[4];
#pragma unroll
      for (int mt = 0; mt < 2; ++mt)
        af[mt] = *(const bf16x8*)(&As[wm * 32 + mt * 16 + l15][((s * 4 + lq) ^ xs) * 8]);
#pragma unroll
      for (int nt = 0; nt < 4; ++nt) {
        const int row = wn * 64 + nt * 16 + l15;
        if (WBF16)
          bfv[nt] = *(const bf16x8*)(&Bs[row * 64 + (((s * 4 + lq) ^ xs) * 8)]);
        else
          bfv[nt] = *(const bf16x8*)(&Bs[row * 72 + s * 32 + lq * 8]);
      }
#pragma unroll
      for (int mt = 0; mt < 2; ++mt)
#pragma unroll
        for (int nt = 0; nt < 4; ++nt)
          acc[mt][nt] = __builtin_amdgcn_mfma_f32_16x16x32_bf16(
              af[mt], bfv[nt], acc[mt][nt], 0, 0, 0);
    }
    __syncthreads();
  }

#pragma unroll
  for (int mt = 0; mt < 2; ++mt) {
    const int mg_base = m0 + wm * 32 + mt * 16 + lq * 4;
    const int b = mg_base >> 10, nr0 = mg_base & 1023;
#pragma unroll
    for (int nt = 0; nt < 4; ++nt) {
      const int ng = n0 + wn * 64 + nt * 16 + l15;
      const float bv = bias[ng];
      const int h = ng >> 6, dd = ng & 63;
      if (z != 2) {
#pragma unroll
        for (int r = 0; r < 4; ++r) {
          const int mg = mg_base + r;
          const size_t idx =
              ((size_t)(b * 16 + h) << 16) + (size_t)(mg & 1023) * 64 + dd;
          C[idx] = (__bf16)((acc[mt][nt][r] + bv) * scale);
        }
      } else {
        bf16x4 o4 = {(__bf16)(acc[mt][nt][0] + bv), (__bf16)(acc[mt][nt][1] + bv),
                     (__bf16)(acc[mt][nt][2] + bv), (__bf16)(acc[mt][nt][3] + bv)};
        *(bf16x4*)(&C[((size_t)(b * 16 + h) << 16) + (size_t)dd * 1024 + nr0]) = o4;
      }
    }
  }
}

// ---------------------------------------------------------------------------
// Out projection: out[4096,1024] fp32 = O @ Wo^T + bo.  64x64 tile, grid
// (16,64)=1024 blocks (4/CU), 4 waves 2x2 (wave 32x32).  glds+swizzle.
// ---------------------------------------------------------------------------
__global__ __launch_bounds__(256) void gemm_out(const __bf16* __restrict__ A,
                                                const __bf16* __restrict__ W,
                                                const float* __restrict__ bias,
                                                float* __restrict__ C) {
  __shared__ __attribute__((aligned(16))) __bf16 As[64][64];
  __shared__ __attribute__((aligned(16))) __bf16 Bs[64][64];

  const int tid = threadIdx.x;
  const int lane = tid & 63, w = tid >> 6;
  const int wm = w >> 1, wn = w & 1;
  const int l15 = lane & 15, lq = lane >> 4;
  const int lr = lane >> 3, lc = lane & 7;
  const int xs = l15 & 7;
  const int m0 = blockIdx.y * 64, n0 = blockIdx.x * 64;

  f32x4 acc[2][2] = {};

  for (int k0 = 0; k0 < 1024; k0 += 64) {
#pragma unroll
    for (int i = 0; i < 2; ++i) {
      const int row = w * 16 + i * 8 + lr;
      glds16(A + (size_t)(m0 + row) * 1024 + k0 + ((lc ^ lr) * 8), &As[row][lc * 8]);
      glds16(W + (size_t)(n0 + row) * 1024 + k0 + ((lc ^ lr) * 8), &Bs[row][lc * 8]);
    }
    __syncthreads();
#pragma unroll
    for (int s = 0; s < 2; ++s) {
      bf16x8 af[2], bfv[2];
#pragma unroll
      for (int mt = 0; mt < 2; ++mt)
        af[mt] = *(const bf16x8*)(&As[wm * 32 + mt * 16 + l15][((s * 4 + lq) ^ xs) * 8]);
#pragma unroll
      for (int nt = 0; nt < 2; ++nt)
        bfv[nt] = *(const bf16x8*)(&Bs[wn * 32 + nt * 16 + l15][((s * 4 + lq) ^ xs) * 8]);
#pragma unroll
      for (int mt = 0; mt < 2; ++mt)
#pragma unroll
        for (int nt = 0; nt < 2; ++nt)
          acc[mt][nt] = __builtin_amdgcn_mfma_f32_16x16x32_bf16(
              af[mt], bfv[nt], acc[mt][nt], 0, 0, 0);
    }
    __syncthreads();
  }

#pragma unroll
  for (int mt = 0; mt < 2; ++mt) {
    const int mg_base = m0 + wm * 32 + mt * 16 + lq * 4;
#pragma unroll
    for (int nt = 0; nt < 2; ++nt) {
      const int ng = n0 + wn * 32 + nt * 16 + l15;
      const float bv = bias[ng];
#pragma unroll
      for (int r = 0; r < 4; ++r)
        C[(size_t)(mg_base + r) * 1024 + ng] = acc[mt][nt][r] + bv;
    }
  }
}

// ---------------------------------------------------------------------------
// Flash attention, S^T orientation, 16 q per wave (64 q per block, 1024
// blocks = 4/CU at 33 KB LDS).  Q pre-scaled by log2(e) -> exp2 softmax
// numerator, no max shift (|logit*log2e| < ~100 << 126; l fits fp32 easily).
// Per (b,h): Q [n,64], K [n,64], Vt [64,n].  Grid (16, 64).
// Reference divides by sqrt(E)=32 AFTER softmax -> fold into /(l*32).
// ---------------------------------------------------------------------------
__global__ __launch_bounds__(256) void attn_kernel(const __bf16* __restrict__ Q,
                                                   const __bf16* __restrict__ K,
                                                   const __bf16* __restrict__ Vt,
                                                   __bf16* __restrict__ O) {
  __shared__ __attribute__((aligned(16))) __bf16 Qs[64][64];
  __shared__ __attribute__((aligned(16))) __bf16 Ks[64][64];
  __shared__ __attribute__((aligned(16))) __bf16 Vs[64][64];
  __shared__ __attribute__((aligned(16))) __bf16 Ps[4][16][72];

  const int tid = threadIdx.x;
  const int lane = tid & 63, w = tid >> 6;
  const int l15 = lane & 15, lq = lane >> 4;
  const int lr = lane >> 3, lc = lane & 7;
  const int xs = l15 & 7;

  const int qt = blockIdx.x;  // 0..15
  const int bh = blockIdx.y;  // 0..63
  const __bf16* Qh = Q + (size_t)bh * 65536;
  const __bf16* Kh = K + (size_t)bh * 65536;
  const __bf16* Vh = Vt + (size_t)bh * 65536;

  // stage Q tile (64x64) once via glds, swizzled
#pragma unroll
  for (int i = 0; i < 2; ++i) {
    const int row = w * 16 + i * 8 + lr;
    glds16(Qh + (size_t)(qt * 64 + row) * 64 + ((lc ^ lr) * 8), &Qs[row][lc * 8]);
  }

  float l_run = 0.0f;
  f32x4 oacc[4] = {};

  for (int kb = 0; kb < 16; ++kb) {
    __syncthreads();  // prev-iter readers done; drains Q glds at kb=0
#pragma unroll
    for (int i = 0; i < 2; ++i) {
      const int row = w * 16 + i * 8 + lr;
      glds16(Kh + (size_t)kb * 4096 + (size_t)row * 64 + ((lc ^ lr) * 8), &Ks[row][lc * 8]);
      glds16(Vh + (size_t)row * 1024 + kb * 64 + ((lc ^ lr) * 8), &Vs[row][lc * 8]);
    }
    __syncthreads();

    // S^T: rows = kseq(64), cols = this wave's 16 q
    f32x4 sacc[4] = {};
#pragma unroll
    for (int s = 0; s < 2; ++s) {
      bf16x8 bq = *(const bf16x8*)(&Qs[w * 16 + l15][((s * 4 + lq) ^ xs) * 8]);
#pragma unroll
      for (int mt = 0; mt < 4; ++mt) {
        bf16x8 ak = *(const bf16x8*)(&Ks[mt * 16 + l15][((s * 4 + lq) ^ xs) * 8]);
        sacc[mt] = __builtin_amdgcn_mfma_f32_16x16x32_bf16(ak, bq, sacc[mt], 0, 0, 0);
      }
    }

    // softmax numerator via exp2 (per-lane q = w*16 + l15)
    float sum = 0.0f;
#pragma unroll
    for (int mt = 0; mt < 4; ++mt)
#pragma unroll
      for (int r = 0; r < 4; ++r) {
        const float e = __builtin_amdgcn_exp2f(sacc[mt][r]);
        sacc[mt][r] = e;
        sum += e;
      }
    sum += __shfl_xor(sum, 16, 64);
    sum += __shfl_xor(sum, 32, 64);
    l_run += sum;

    // P -> LDS row-major [q][k] (padded), lane writes 4 consecutive k (b64)
#pragma unroll
    for (int mt = 0; mt < 4; ++mt) {
      bf16x4 p4 = {(__bf16)sacc[mt][0], (__bf16)sacc[mt][1],
                   (__bf16)sacc[mt][2], (__bf16)sacc[mt][3]};
      *(bf16x4*)(&Ps[w][l15][mt * 16 + lq * 4]) = p4;
    }
    __threadfence_block();  // wave-private P round-trip

    // O^T += Vt · P
#pragma unroll
    for (int s = 0; s < 2; ++s) {
      bf16x8 bp = *(const bf16x8*)(&Ps[w][l15][s * 32 + lq * 8]);
#pragma unroll
      for (int mt = 0; mt < 4; ++mt) {
        bf16x8 av = *(const bf16x8*)(&Vs[mt * 16 + l15][((s * 4 + lq) ^ xs) * 8]);
        oacc[mt] = __builtin_amdgcn_mfma_f32_16x16x32_bf16(av, bp, oacc[mt], 0, 0, 0);
      }
    }
  }

  // epilogue: O^T col=q(l15), row=d=mt*16+lq*4+r; write O[b*1024+q][h*64+d]
  const int b = bh >> 4, h = bh & 15;
  const float inv = 1.0f / (l_run * 32.0f);
  const size_t base = (size_t)(b * 1024 + qt * 64 + w * 16 + l15) * 1024 + h * 64;
#pragma unroll
  for (int mt = 0; mt < 4; ++mt) {
    bf16x4 o4 = {(__bf16)(oacc[mt][0] * inv), (__bf16)(oacc[mt][1] * inv),
                 (__bf16)(oacc[mt][2] * inv), (__bf16)(oacc[mt][3] * inv)};
    *(bf16x4*)(&O[base + mt * 16 + lq * 4]) = o4;
  }
}

// ---------------------------------------------------------------------------
extern "C" void kernel_launch(void* const* d_in, const int* in_sizes, int n_in,
                              void* d_out, int out_size, void* d_ws, size_t ws_size,
                              hipStream_t stream) {
  const float* x  = (const float*)d_in[0];
  const float* Wq = (const float*)d_in[1];
  const float* bq = (const float*)d_in[2];
  const float* Wk = (const float*)d_in[3];
  const float* bk = (const float*)d_in[4];
  const float* Wv = (const float*)d_in[5];
  const float* bv = (const float*)d_in[6];
  const float* Wo = (const float*)d_in[7];
  const float* bo = (const float*)d_in[8];
  float* out = (float*)d_out;

  const size_t SZ = (size_t)4 * 1024 * 1024;  // 4M bf16 per slot (8 MB)
  __bf16* Qw = (__bf16*)d_ws;
  __bf16* Kw = Qw + SZ;
  __bf16* Vw = Kw + SZ;
  __bf16* s3 = Vw + SZ;  // xb during QKV, then Ow
  __bf16* xb = s3;
  __bf16* Ow = s3;

  dim3 blk(256);

  if (ws_size >= (size_t)40 * 1024 * 1024) {
    __bf16* Wqb = s3 + SZ;  // 2 MB each
    __bf16* Wkb = Wqb + SZ / 4;
    __bf16* Wvb = Wkb + SZ / 4;
    __bf16* Wob = Wvb + SZ / 4;
    cvt_all<<<8192, blk, 0, stream>>>(x, Wq, Wk, Wv, Wo, xb, Wqb, Wkb, Wvb, Wob);
    gemm_qkv<true><<<dim3(8, 64, 3), blk, 0, stream>>>(xb, Wqb, Wkb, Wvb,
                                                       bq, bk, bv, Qw, Kw, Vw);
    attn_kernel<<<dim3(16, 64), blk, 0, stream>>>(Qw, Kw, Vw, Ow);
    gemm_out<<<dim3(16, 64), blk, 0, stream>>>(Ow, Wob, bo, out);
  } else {
    __bf16* Wob = Kw;  // Kw dead after attention
    cvt_f32_bf16<<<4096, blk, 0, stream>>>(x, xb, 1048576);
    gemm_qkv<false><<<dim3(8, 64, 3), blk, 0, stream>>>(xb, Wq, Wk, Wv,
                                                        bq, bk, bv, Qw, Kw, Vw);
    attn_kernel<<<dim3(16, 64), blk, 0, stream>>>(Qw, Kw, Vw, Ow);
    cvt_f32_bf16<<<1024, blk, 0, stream>>>(Wo, Wob, 262144);
    gemm_out<<<dim3(16, 64), blk, 0, stream>>>(Ow, Wob, bo, out);
  }
}

// Round 11
// 174.732 us; speedup vs baseline: 1.0516x; 1.0075x over previous
//
#include <hip/hip_runtime.h>
#include <hip/hip_bf16.h>

// MHA: B=4, N=1024, E=1024, H=16, d=64.  fp32 I/O, bf16 MFMA internals.
//
// Round 11: XCD-aware block mapping (XCD = linear_block_id % 8 assumption):
//  - qkv: 1D grid 1536; each XCD gets 16 m-blocks x 4 n-blocks x 3 z
//    (xb duplication 8x -> 2x across XCD L2s).
//  - attn: grid (bh=64, qt=16) so all qt-blocks of a head share an XCD
//    (K/V L2-local).
//  - gemm_out: grid (m=64, n=16) so O-tiles are XCD-local.
// Everything else identical to round 10 (16q attn, exp2 softmax, 64x64 out,
// glds+swizzle, weights pre-converted).
//
// XOR-swizzled [row][64] LDS tiles: LDS[row][c8] holds G[row][c8 ^ (row&7)];
// frag readers XOR with l15&7.  Staging via global_load_lds(16B).
//
// ws (40 MB fast path): [Qw 8M][Kw 8M][Vw 8M][xb/Ow 8M][Wqb][Wkb][Wvb][Wob]
// (2 MB each).  ws_size < 40 MB -> fp32-W fallback (deterministic branch).
//
// MFMA m89/m91 layouts: A-frag A[m=l&15][k=(l>>4)*8+j]; B-frag same addressing
// from row-major [n][k]; C/D col=l&15, row=(l>>4)*4+reg.

typedef __bf16 bf16x8 __attribute__((ext_vector_type(8)));
typedef __bf16 bf16x4 __attribute__((ext_vector_type(4)));
typedef float  f32x4  __attribute__((ext_vector_type(4)));

#define LOG2E 1.44269504f

__device__ __forceinline__ void glds16(const __bf16* g, __bf16* l) {
  __builtin_amdgcn_global_load_lds(
      (const __attribute__((address_space(1))) void*)g,
      (__attribute__((address_space(3))) void*)l, 16, 0, 0);
}

__global__ __launch_bounds__(256) void cvt_f32_bf16(const float* __restrict__ in,
                                                    __bf16* __restrict__ out, int n4) {
  int i = blockIdx.x * 256 + threadIdx.x;
  if (i < n4) {
    float4 v = *(const float4*)(in + (size_t)i * 4);
    bf16x4 b = {(__bf16)v.x, (__bf16)v.y, (__bf16)v.z, (__bf16)v.w};
    *(bf16x4*)(out + (size_t)i * 4) = b;
  }
}

// Fused conversion: x (1M float4) + Wq/Wk/Wv/Wo (256K float4 each).
__global__ __launch_bounds__(256) void cvt_all(const float* __restrict__ x,
                                               const float* __restrict__ Wq,
                                               const float* __restrict__ Wk,
                                               const float* __restrict__ Wv,
                                               const float* __restrict__ Wo,
                                               __bf16* __restrict__ xb,
                                               __bf16* __restrict__ Wqb,
                                               __bf16* __restrict__ Wkb,
                                               __bf16* __restrict__ Wvb,
                                               __bf16* __restrict__ Wob) {
  const int i = blockIdx.x * 256 + threadIdx.x;  // 0..2097151
  const float* src;
  __bf16* dst;
  int off;
  if (i < 1048576) {
    src = x; dst = xb; off = i;
  } else {
    const int j = i - 1048576;
    const int seg = j >> 18;  // 0..3
    off = j & 262143;
    src = (seg == 0) ? Wq : (seg == 1) ? Wk : (seg == 2) ? Wv : Wo;
    dst = (seg == 0) ? Wqb : (seg == 1) ? Wkb : (seg == 2) ? Wvb : Wob;
  }
  float4 v = *(const float4*)(src + (size_t)off * 4);
  bf16x4 b = {(__bf16)v.x, (__bf16)v.y, (__bf16)v.z, (__bf16)v.w};
  *(bf16x4*)(dst + (size_t)off * 4) = b;
}

// ---------------------------------------------------------------------------
// Fused QKV projection, 64x128 tile, BK=64, 1D grid 1536 (6 blocks/CU).
// XCD decomposition: c=bid&7 -> (a=c>>2, b=c&3); XCD c covers m-blocks
// b*16..b*16+15, n-blocks a*4..a*4+3, all z.  Coverage is an exact partition.
// z=0/1/2 -> Q/K (head layout [b,h,n,d]), V (transposed [b,h,d,n]).
// Q epilogue scaled by log2(e) so attn can use exp2 directly.
// ---------------------------------------------------------------------------
template <bool WBF16>
__global__ __launch_bounds__(256) void gemm_qkv(const __bf16* __restrict__ A,
                                                const void* __restrict__ Wqp,
                                                const void* __restrict__ Wkp,
                                                const void* __restrict__ Wvp,
                                                const float* __restrict__ bq,
                                                const float* __restrict__ bk,
                                                const float* __restrict__ bv,
                                                __bf16* __restrict__ Qw,
                                                __bf16* __restrict__ Kw,
                                                __bf16* __restrict__ Vw) {
  constexpr int BST = WBF16 ? 64 : 72;
  __shared__ __attribute__((aligned(16))) __bf16 As[64][64];
  __shared__ __attribute__((aligned(16))) __bf16 Bs[128 * BST];

  const int tid = threadIdx.x;
  const int lane = tid & 63, w = tid >> 6;
  const int wm = w >> 1, wn = w & 1;
  const int l15 = lane & 15, lq = lane >> 4;
  const int lr = lane >> 3, lc = lane & 7;
  const int xs = l15 & 7;

  // XCD-aware decomposition of 1536 blocks
  const int bid = blockIdx.x;
  const int c = bid & 7, t = bid >> 3;   // c = presumed XCD, t = 0..191
  const int a = c >> 2, b2 = c & 3;
  const int z = t >> 6;                  // 0..2
  const int r = t & 63;
  const int mb = b2 * 16 + (r & 15);     // 0..63
  const int nb = a * 4 + (r >> 4);       // 0..7
  const int m0 = mb * 64, n0 = nb * 128;

  const void* Wp = (z == 0) ? Wqp : (z == 1) ? Wkp : Wvp;
  const float* bias = (z == 0) ? bq : (z == 1) ? bk : bv;
  __bf16* C = (z == 0) ? Qw : (z == 1) ? Kw : Vw;
  const float scale = (z == 0) ? LOG2E : 1.0f;

  f32x4 acc[2][4] = {};

  for (int k0 = 0; k0 < 1024; k0 += 64) {
#pragma unroll
    for (int i = 0; i < 2; ++i) {
      const int row = w * 16 + i * 8 + lr;
      glds16(A + (size_t)(m0 + row) * 1024 + k0 + ((lc ^ lr) * 8), &As[row][lc * 8]);
    }
    if (WBF16) {
      const __bf16* Wb = (const __bf16*)Wp;
#pragma unroll
      for (int i = 0; i < 4; ++i) {
        const int row = w * 32 + i * 8 + lr;
        glds16(Wb + (size_t)(n0 + row) * 1024 + k0 + ((lc ^ lr) * 8), &Bs[row * 64 + lc * 8]);
      }
    } else {
      const float* W = (const float*)Wp;
#pragma unroll
      for (int i = 0; i < 8; ++i) {
        const int cc = i * 256 + tid, row = cc >> 4, col = (cc & 15) * 4;
        float4 wv = *(const float4*)(W + (size_t)(n0 + row) * 1024 + k0 + col);
        bf16x4 b4 = {(__bf16)wv.x, (__bf16)wv.y, (__bf16)wv.z, (__bf16)wv.w};
        *(bf16x4*)(&Bs[row * 72 + col]) = b4;
      }
    }
    __syncthreads();
#pragma unroll
    for (int s = 0; s < 2; ++s) {
      bf16x8 af[2], bfv[4];
#pragma unroll
      for (int mt = 0; mt < 2; ++mt)
        af[mt] = *(const bf16x8*)(&As[wm * 32 + mt * 16 + l15][((s * 4 + lq) ^ xs) * 8]);
#pragma unroll
      for (int nt = 0; nt < 4; ++nt) {
        const int row = wn * 64 + nt * 16 + l15;
        if (WBF16)
          bfv[nt] = *(const bf16x8*)(&Bs[row * 64 + (((s * 4 + lq) ^ xs) * 8)]);
        else
          bfv[nt] = *(const bf16x8*)(&Bs[row * 72 + s * 32 + lq * 8]);
      }
#pragma unroll
      for (int mt = 0; mt < 2; ++mt)
#pragma unroll
        for (int nt = 0; nt < 4; ++nt)
          acc[mt][nt] = __builtin_amdgcn_mfma_f32_16x16x32_bf16(
              af[mt], bfv[nt], acc[mt][nt], 0, 0, 0);
    }
    __syncthreads();
  }

#pragma unroll
  for (int mt = 0; mt < 2; ++mt) {
    const int mg_base = m0 + wm * 32 + mt * 16 + lq * 4;
    const int bb = mg_base >> 10, nr0 = mg_base & 1023;
#pragma unroll
    for (int nt = 0; nt < 4; ++nt) {
      const int ng = n0 + wn * 64 + nt * 16 + l15;
      const float bv = bias[ng];
      const int h = ng >> 6, dd = ng & 63;
      if (z != 2) {
#pragma unroll
        for (int rr = 0; rr < 4; ++rr) {
          const int mg = mg_base + rr;
          const size_t idx =
              ((size_t)(bb * 16 + h) << 16) + (size_t)(mg & 1023) * 64 + dd;
          C[idx] = (__bf16)((acc[mt][nt][rr] + bv) * scale);
        }
      } else {
        bf16x4 o4 = {(__bf16)(acc[mt][nt][0] + bv), (__bf16)(acc[mt][nt][1] + bv),
                     (__bf16)(acc[mt][nt][2] + bv), (__bf16)(acc[mt][nt][3] + bv)};
        *(bf16x4*)(&C[((size_t)(bb * 16 + h) << 16) + (size_t)dd * 1024 + nr0]) = o4;
      }
    }
  }
}

// ---------------------------------------------------------------------------
// Out projection: out[4096,1024] fp32 = O @ Wo^T + bo.  64x64 tile, grid
// (m=64, n=16) so O-tiles are XCD-local.  4 waves 2x2 (wave 32x32).
// ---------------------------------------------------------------------------
__global__ __launch_bounds__(256) void gemm_out(const __bf16* __restrict__ A,
                                                const __bf16* __restrict__ W,
                                                const float* __restrict__ bias,
                                                float* __restrict__ C) {
  __shared__ __attribute__((aligned(16))) __bf16 As[64][64];
  __shared__ __attribute__((aligned(16))) __bf16 Bs[64][64];

  const int tid = threadIdx.x;
  const int lane = tid & 63, w = tid >> 6;
  const int wm = w >> 1, wn = w & 1;
  const int l15 = lane & 15, lq = lane >> 4;
  const int lr = lane >> 3, lc = lane & 7;
  const int xs = l15 & 7;
  const int m0 = blockIdx.x * 64, n0 = blockIdx.y * 64;  // m on x: XCD-local O

  f32x4 acc[2][2] = {};

  for (int k0 = 0; k0 < 1024; k0 += 64) {
#pragma unroll
    for (int i = 0; i < 2; ++i) {
      const int row = w * 16 + i * 8 + lr;
      glds16(A + (size_t)(m0 + row) * 1024 + k0 + ((lc ^ lr) * 8), &As[row][lc * 8]);
      glds16(W + (size_t)(n0 + row) * 1024 + k0 + ((lc ^ lr) * 8), &Bs[row][lc * 8]);
    }
    __syncthreads();
#pragma unroll
    for (int s = 0; s < 2; ++s) {
      bf16x8 af[2], bfv[2];
#pragma unroll
      for (int mt = 0; mt < 2; ++mt)
        af[mt] = *(const bf16x8*)(&As[wm * 32 + mt * 16 + l15][((s * 4 + lq) ^ xs) * 8]);
#pragma unroll
      for (int nt = 0; nt < 2; ++nt)
        bfv[nt] = *(const bf16x8*)(&Bs[wn * 32 + nt * 16 + l15][((s * 4 + lq) ^ xs) * 8]);
#pragma unroll
      for (int mt = 0; mt < 2; ++mt)
#pragma unroll
        for (int nt = 0; nt < 2; ++nt)
          acc[mt][nt] = __builtin_amdgcn_mfma_f32_16x16x32_bf16(
              af[mt], bfv[nt], acc[mt][nt], 0, 0, 0);
    }
    __syncthreads();
  }

#pragma unroll
  for (int mt = 0; mt < 2; ++mt) {
    const int mg_base = m0 + wm * 32 + mt * 16 + lq * 4;
#pragma unroll
    for (int nt = 0; nt < 2; ++nt) {
      const int ng = n0 + wn * 32 + nt * 16 + l15;
      const float bv = bias[ng];
#pragma unroll
      for (int r = 0; r < 4; ++r)
        C[(size_t)(mg_base + r) * 1024 + ng] = acc[mt][nt][r] + bv;
    }
  }
}

// ---------------------------------------------------------------------------
// Flash attention, S^T orientation, 16 q per wave (64 q per block, 1024
// blocks = 4/CU at 33 KB LDS).  Grid (bh=64, qt=16): all qt-blocks of a head
// share an XCD -> K/V L2-local.  Q pre-scaled by log2(e) -> exp2 softmax,
// no max shift.  Reference divides by sqrt(E)=32 AFTER softmax -> /(l*32).
// ---------------------------------------------------------------------------
__global__ __launch_bounds__(256) void attn_kernel(const __bf16* __restrict__ Q,
                                                   const __bf16* __restrict__ K,
                                                   const __bf16* __restrict__ Vt,
                                                   __bf16* __restrict__ O) {
  __shared__ __attribute__((aligned(16))) __bf16 Qs[64][64];
  __shared__ __attribute__((aligned(16))) __bf16 Ks[64][64];
  __shared__ __attribute__((aligned(16))) __bf16 Vs[64][64];
  __shared__ __attribute__((aligned(16))) __bf16 Ps[4][16][72];

  const int tid = threadIdx.x;
  const int lane = tid & 63, w = tid >> 6;
  const int l15 = lane & 15, lq = lane >> 4;
  const int lr = lane >> 3, lc = lane & 7;
  const int xs = l15 & 7;

  const int bh = blockIdx.x;  // 0..63  (x so same-head blocks share an XCD)
  const int qt = blockIdx.y;  // 0..15
  const __bf16* Qh = Q + (size_t)bh * 65536;
  const __bf16* Kh = K + (size_t)bh * 65536;
  const __bf16* Vh = Vt + (size_t)bh * 65536;

  // stage Q tile (64x64) once via glds, swizzled
#pragma unroll
  for (int i = 0; i < 2; ++i) {
    const int row = w * 16 + i * 8 + lr;
    glds16(Qh + (size_t)(qt * 64 + row) * 64 + ((lc ^ lr) * 8), &Qs[row][lc * 8]);
  }

  float l_run = 0.0f;
  f32x4 oacc[4] = {};

  for (int kb = 0; kb < 16; ++kb) {
    __syncthreads();  // prev-iter readers done; drains Q glds at kb=0
#pragma unroll
    for (int i = 0; i < 2; ++i) {
      const int row = w * 16 + i * 8 + lr;
      glds16(Kh + (size_t)kb * 4096 + (size_t)row * 64 + ((lc ^ lr) * 8), &Ks[row][lc * 8]);
      glds16(Vh + (size_t)row * 1024 + kb * 64 + ((lc ^ lr) * 8), &Vs[row][lc * 8]);
    }
    __syncthreads();

    // S^T: rows = kseq(64), cols = this wave's 16 q
    f32x4 sacc[4] = {};
#pragma unroll
    for (int s = 0; s < 2; ++s) {
      bf16x8 bq = *(const bf16x8*)(&Qs[w * 16 + l15][((s * 4 + lq) ^ xs) * 8]);
#pragma unroll
      for (int mt = 0; mt < 4; ++mt) {
        bf16x8 ak = *(const bf16x8*)(&Ks[mt * 16 + l15][((s * 4 + lq) ^ xs) * 8]);
        sacc[mt] = __builtin_amdgcn_mfma_f32_16x16x32_bf16(ak, bq, sacc[mt], 0, 0, 0);
      }
    }

    // softmax numerator via exp2 (per-lane q = w*16 + l15)
    float sum = 0.0f;
#pragma unroll
    for (int mt = 0; mt < 4; ++mt)
#pragma unroll
      for (int r = 0; r < 4; ++r) {
        const float e = __builtin_amdgcn_exp2f(sacc[mt][r]);
        sacc[mt][r] = e;
        sum += e;
      }
    sum += __shfl_xor(sum, 16, 64);
    sum += __shfl_xor(sum, 32, 64);
    l_run += sum;

    // P -> LDS row-major [q][k] (padded), lane writes 4 consecutive k (b64)
#pragma unroll
    for (int mt = 0; mt < 4; ++mt) {
      bf16x4 p4 = {(__bf16)sacc[mt][0], (__bf16)sacc[mt][1],
                   (__bf16)sacc[mt][2], (__bf16)sacc[mt][3]};
      *(bf16x4*)(&Ps[w][l15][mt * 16 + lq * 4]) = p4;
    }
    __threadfence_block();  // wave-private P round-trip

    // O^T += Vt · P
#pragma unroll
    for (int s = 0; s < 2; ++s) {
      bf16x8 bp = *(const bf16x8*)(&Ps[w][l15][s * 32 + lq * 8]);
#pragma unroll
      for (int mt = 0; mt < 4; ++mt) {
        bf16x8 av = *(const bf16x8*)(&Vs[mt * 16 + l15][((s * 4 + lq) ^ xs) * 8]);
        oacc[mt] = __builtin_amdgcn_mfma_f32_16x16x32_bf16(av, bp, oacc[mt], 0, 0, 0);
      }
    }
  }

  // epilogue: O^T col=q(l15), row=d=mt*16+lq*4+r; write O[b*1024+q][h*64+d]
  const int b = bh >> 4, h = bh & 15;
  const float inv = 1.0f / (l_run * 32.0f);
  const size_t base = (size_t)(b * 1024 + qt * 64 + w * 16 + l15) * 1024 + h * 64;
#pragma unroll
  for (int mt = 0; mt < 4; ++mt) {
    bf16x4 o4 = {(__bf16)(oacc[mt][0] * inv), (__bf16)(oacc[mt][1] * inv),
                 (__bf16)(oacc[mt][2] * inv), (__bf16)(oacc[mt][3] * inv)};
    *(bf16x4*)(&O[base + mt * 16 + lq * 4]) = o4;
  }
}

// ---------------------------------------------------------------------------
extern "C" void kernel_launch(void* const* d_in, const int* in_sizes, int n_in,
                              void* d_out, int out_size, void* d_ws, size_t ws_size,
                              hipStream_t stream) {
  const float* x  = (const float*)d_in[0];
  const float* Wq = (const float*)d_in[1];
  const float* bq = (const float*)d_in[2];
  const float* Wk = (const float*)d_in[3];
  const float* bk = (const float*)d_in[4];
  const float* Wv = (const float*)d_in[5];
  const float* bv = (const float*)d_in[6];
  const float* Wo = (const float*)d_in[7];
  const float* bo = (const float*)d_in[8];
  float* out = (float*)d_out;

  const size_t SZ = (size_t)4 * 1024 * 1024;  // 4M bf16 per slot (8 MB)
  __bf16* Qw = (__bf16*)d_ws;
  __bf16* Kw = Qw + SZ;
  __bf16* Vw = Kw + SZ;
  __bf16* s3 = Vw + SZ;  // xb during QKV, then Ow
  __bf16* xb = s3;
  __bf16* Ow = s3;

  dim3 blk(256);

  if (ws_size >= (size_t)40 * 1024 * 1024) {
    __bf16* Wqb = s3 + SZ;  // 2 MB each
    __bf16* Wkb = Wqb + SZ / 4;
    __bf16* Wvb = Wkb + SZ / 4;
    __bf16* Wob = Wvb + SZ / 4;
    cvt_all<<<8192, blk, 0, stream>>>(x, Wq, Wk, Wv, Wo, xb, Wqb, Wkb, Wvb, Wob);
    gemm_qkv<true><<<dim3(1536), blk, 0, stream>>>(xb, Wqb, Wkb, Wvb,
                                                   bq, bk, bv, Qw, Kw, Vw);
    attn_kernel<<<dim3(64, 16), blk, 0, stream>>>(Qw, Kw, Vw, Ow);
    gemm_out<<<dim3(64, 16), blk, 0, stream>>>(Ow, Wob, bo, out);
  } else {
    __bf16* Wob = Kw;  // Kw dead after attention
    cvt_f32_bf16<<<4096, blk, 0, stream>>>(x, xb, 1048576);
    gemm_qkv<false><<<dim3(1536), blk, 0, stream>>>(xb, Wq, Wk, Wv,
                                                    bq, bk, bv, Qw, Kw, Vw);
    attn_kernel<<<dim3(64, 16), blk, 0, stream>>>(Qw, Kw, Vw, Ow);
    cvt_f32_bf16<<<1024, blk, 0, stream>>>(Wo, Wob, 262144);
    gemm_out<<<dim3(64, 16), blk, 0, stream>>>(Ow, Wob, bo, out);
  }
}

// Round 12
// 172.519 us; speedup vs baseline: 1.0651x; 1.0128x over previous
//
#include <hip/hip_runtime.h>
#include <hip/hip_bf16.h>

// MHA: B=4, N=1024, E=1024, H=16, d=64.  fp32 I/O, bf16 MFMA internals.
//
// Round 12: (1) gemm_out 32x128 tile, grid (128,8) -> 8 blocks/CU (max 32
// waves/CU); (2) attn hoists loop-invariant Q fragments into registers.
// Everything else = round 11 (XCD-aware mapping, 16q attn, exp2 softmax,
// glds+swizzle, weights pre-converted).
//
// XOR-swizzled [row][64] LDS tiles: LDS[row][c8] holds G[row][c8 ^ (row&7)];
// frag readers XOR with l15&7.  Staging via global_load_lds(16B).
//
// ws (40 MB fast path): [Qw 8M][Kw 8M][Vw 8M][xb/Ow 8M][Wqb][Wkb][Wvb][Wob]
// (2 MB each).  ws_size < 40 MB -> fp32-W fallback (deterministic branch).
//
// MFMA m89/m91 layouts: A-frag A[m=l&15][k=(l>>4)*8+j]; B-frag same addressing
// from row-major [n][k]; C/D col=l&15, row=(l>>4)*4+reg.

typedef __bf16 bf16x8 __attribute__((ext_vector_type(8)));
typedef __bf16 bf16x4 __attribute__((ext_vector_type(4)));
typedef float  f32x4  __attribute__((ext_vector_type(4)));

#define LOG2E 1.44269504f

__device__ __forceinline__ void glds16(const __bf16* g, __bf16* l) {
  __builtin_amdgcn_global_load_lds(
      (const __attribute__((address_space(1))) void*)g,
      (__attribute__((address_space(3))) void*)l, 16, 0, 0);
}

__global__ __launch_bounds__(256) void cvt_f32_bf16(const float* __restrict__ in,
                                                    __bf16* __restrict__ out, int n4) {
  int i = blockIdx.x * 256 + threadIdx.x;
  if (i < n4) {
    float4 v = *(const float4*)(in + (size_t)i * 4);
    bf16x4 b = {(__bf16)v.x, (__bf16)v.y, (__bf16)v.z, (__bf16)v.w};
    *(bf16x4*)(out + (size_t)i * 4) = b;
  }
}

// Fused conversion: x (1M float4) + Wq/Wk/Wv/Wo (256K float4 each).
__global__ __launch_bounds__(256) void cvt_all(const float* __restrict__ x,
                                               const float* __restrict__ Wq,
                                               const float* __restrict__ Wk,
                                               const float* __restrict__ Wv,
                                               const float* __restrict__ Wo,
                                               __bf16* __restrict__ xb,
                                               __bf16* __restrict__ Wqb,
                                               __bf16* __restrict__ Wkb,
                                               __bf16* __restrict__ Wvb,
                                               __bf16* __restrict__ Wob) {
  const int i = blockIdx.x * 256 + threadIdx.x;  // 0..2097151
  const float* src;
  __bf16* dst;
  int off;
  if (i < 1048576) {
    src = x; dst = xb; off = i;
  } else {
    const int j = i - 1048576;
    const int seg = j >> 18;  // 0..3
    off = j & 262143;
    src = (seg == 0) ? Wq : (seg == 1) ? Wk : (seg == 2) ? Wv : Wo;
    dst = (seg == 0) ? Wqb : (seg == 1) ? Wkb : (seg == 2) ? Wvb : Wob;
  }
  float4 v = *(const float4*)(src + (size_t)off * 4);
  bf16x4 b = {(__bf16)v.x, (__bf16)v.y, (__bf16)v.z, (__bf16)v.w};
  *(bf16x4*)(dst + (size_t)off * 4) = b;
}

// ---------------------------------------------------------------------------
// Fused QKV projection, 64x128 tile, BK=64, 1D grid 1536 (6 blocks/CU).
// XCD decomposition: c=bid&7 -> (a=c>>2, b=c&3); XCD c covers m-blocks
// b*16..b*16+15, n-blocks a*4..a*4+3, all z.
// z=0/1/2 -> Q/K (head layout [b,h,n,d]), V (transposed [b,h,d,n]).
// Q epilogue scaled by log2(e) so attn can use exp2 directly.
// ---------------------------------------------------------------------------
template <bool WBF16>
__global__ __launch_bounds__(256) void gemm_qkv(const __bf16* __restrict__ A,
                                                const void* __restrict__ Wqp,
                                                const void* __restrict__ Wkp,
                                                const void* __restrict__ Wvp,
                                                const float* __restrict__ bq,
                                                const float* __restrict__ bk,
                                                const float* __restrict__ bv,
                                                __bf16* __restrict__ Qw,
                                                __bf16* __restrict__ Kw,
                                                __bf16* __restrict__ Vw) {
  constexpr int BST = WBF16 ? 64 : 72;
  __shared__ __attribute__((aligned(16))) __bf16 As[64][64];
  __shared__ __attribute__((aligned(16))) __bf16 Bs[128 * BST];

  const int tid = threadIdx.x;
  const int lane = tid & 63, w = tid >> 6;
  const int wm = w >> 1, wn = w & 1;
  const int l15 = lane & 15, lq = lane >> 4;
  const int lr = lane >> 3, lc = lane & 7;
  const int xs = l15 & 7;

  const int bid = blockIdx.x;
  const int c = bid & 7, t = bid >> 3;
  const int a = c >> 2, b2 = c & 3;
  const int z = t >> 6;
  const int r = t & 63;
  const int mb = b2 * 16 + (r & 15);
  const int nb = a * 4 + (r >> 4);
  const int m0 = mb * 64, n0 = nb * 128;

  const void* Wp = (z == 0) ? Wqp : (z == 1) ? Wkp : Wvp;
  const float* bias = (z == 0) ? bq : (z == 1) ? bk : bv;
  __bf16* C = (z == 0) ? Qw : (z == 1) ? Kw : Vw;
  const float scale = (z == 0) ? LOG2E : 1.0f;

  f32x4 acc[2][4] = {};

  for (int k0 = 0; k0 < 1024; k0 += 64) {
#pragma unroll
    for (int i = 0; i < 2; ++i) {
      const int row = w * 16 + i * 8 + lr;
      glds16(A + (size_t)(m0 + row) * 1024 + k0 + ((lc ^ lr) * 8), &As[row][lc * 8]);
    }
    if (WBF16) {
      const __bf16* Wb = (const __bf16*)Wp;
#pragma unroll
      for (int i = 0; i < 4; ++i) {
        const int row = w * 32 + i * 8 + lr;
        glds16(Wb + (size_t)(n0 + row) * 1024 + k0 + ((lc ^ lr) * 8), &Bs[row * 64 + lc * 8]);
      }
    } else {
      const float* W = (const float*)Wp;
#pragma unroll
      for (int i = 0; i < 8; ++i) {
        const int cc = i * 256 + tid, row = cc >> 4, col = (cc & 15) * 4;
        float4 wv = *(const float4*)(W + (size_t)(n0 + row) * 1024 + k0 + col);
        bf16x4 b4 = {(__bf16)wv.x, (__bf16)wv.y, (__bf16)wv.z, (__bf16)wv.w};
        *(bf16x4*)(&Bs[row * 72 + col]) = b4;
      }
    }
    __syncthreads();
#pragma unroll
    for (int s = 0; s < 2; ++s) {
      bf16x8 af[2], bfv[4];
#pragma unroll
      for (int mt = 0; mt < 2; ++mt)
        af[mt] = *(const bf16x8*)(&As[wm * 32 + mt * 16 + l15][((s * 4 + lq) ^ xs) * 8]);
#pragma unroll
      for (int nt = 0; nt < 4; ++nt) {
        const int row = wn * 64 + nt * 16 + l15;
        if (WBF16)
          bfv[nt] = *(const bf16x8*)(&Bs[row * 64 + (((s * 4 + lq) ^ xs) * 8)]);
        else
          bfv[nt] = *(const bf16x8*)(&Bs[row * 72 + s * 32 + lq * 8]);
      }
#pragma unroll
      for (int mt = 0; mt < 2; ++mt)
#pragma unroll
        for (int nt = 0; nt < 4; ++nt)
          acc[mt][nt] = __builtin_amdgcn_mfma_f32_16x16x32_bf16(
              af[mt], bfv[nt], acc[mt][nt], 0, 0, 0);
    }
    __syncthreads();
  }

#pragma unroll
  for (int mt = 0; mt < 2; ++mt) {
    const int mg_base = m0 + wm * 32 + mt * 16 + lq * 4;
    const int bb = mg_base >> 10, nr0 = mg_base & 1023;
#pragma unroll
    for (int nt = 0; nt < 4; ++nt) {
      const int ng = n0 + wn * 64 + nt * 16 + l15;
      const float bv = bias[ng];
      const int h = ng >> 6, dd = ng & 63;
      if (z != 2) {
#pragma unroll
        for (int rr = 0; rr < 4; ++rr) {
          const int mg = mg_base + rr;
          const size_t idx =
              ((size_t)(bb * 16 + h) << 16) + (size_t)(mg & 1023) * 64 + dd;
          C[idx] = (__bf16)((acc[mt][nt][rr] + bv) * scale);
        }
      } else {
        bf16x4 o4 = {(__bf16)(acc[mt][nt][0] + bv), (__bf16)(acc[mt][nt][1] + bv),
                     (__bf16)(acc[mt][nt][2] + bv), (__bf16)(acc[mt][nt][3] + bv)};
        *(bf16x4*)(&C[((size_t)(bb * 16 + h) << 16) + (size_t)dd * 1024 + nr0]) = o4;
      }
    }
  }
}

// ---------------------------------------------------------------------------
// Out projection: out[4096,1024] fp32 = O @ Wo^T + bo.  32x128 tile, grid
// (m=128, n=8) = 1024 blocks, LDS 20.5 KB -> 8 blocks/CU (32 waves/CU).
// 4 waves 2x2: wave tile 16x64 (acc 1x4).  All n-blocks of a row-block share
// an XCD under lin%8 (A fetched once; W 8x).
// ---------------------------------------------------------------------------
__global__ __launch_bounds__(256) void gemm_out(const __bf16* __restrict__ A,
                                                const __bf16* __restrict__ W,
                                                const float* __restrict__ bias,
                                                float* __restrict__ C) {
  __shared__ __attribute__((aligned(16))) __bf16 As[32][64];
  __shared__ __attribute__((aligned(16))) __bf16 Bs[128][64];

  const int tid = threadIdx.x;
  const int lane = tid & 63, w = tid >> 6;
  const int wm = w >> 1, wn = w & 1;
  const int l15 = lane & 15, lq = lane >> 4;
  const int lr = lane >> 3, lc = lane & 7;
  const int xs = l15 & 7;
  const int m0 = blockIdx.x * 32, n0 = blockIdx.y * 128;

  f32x4 acc[4] = {};

  for (int k0 = 0; k0 < 1024; k0 += 64) {
    {  // A: wave w stages rows w*8..+7 (1 glds/lane)
      const int row = w * 8 + lr;
      glds16(A + (size_t)(m0 + row) * 1024 + k0 + ((lc ^ lr) * 8), &As[row][lc * 8]);
    }
#pragma unroll
    for (int i = 0; i < 4; ++i) {  // B: wave w rows w*32..+31
      const int row = w * 32 + i * 8 + lr;
      glds16(W + (size_t)(n0 + row) * 1024 + k0 + ((lc ^ lr) * 8), &Bs[row][lc * 8]);
    }
    __syncthreads();
#pragma unroll
    for (int s = 0; s < 2; ++s) {
      bf16x8 af = *(const bf16x8*)(&As[wm * 16 + l15][((s * 4 + lq) ^ xs) * 8]);
#pragma unroll
      for (int nt = 0; nt < 4; ++nt) {
        bf16x8 bfv = *(const bf16x8*)(&Bs[wn * 64 + nt * 16 + l15][((s * 4 + lq) ^ xs) * 8]);
        acc[nt] = __builtin_amdgcn_mfma_f32_16x16x32_bf16(af, bfv, acc[nt], 0, 0, 0);
      }
    }
    __syncthreads();
  }

  const int mg_base = m0 + wm * 16 + lq * 4;
#pragma unroll
  for (int nt = 0; nt < 4; ++nt) {
    const int ng = n0 + wn * 64 + nt * 16 + l15;
    const float bv = bias[ng];
#pragma unroll
    for (int r = 0; r < 4; ++r)
      C[(size_t)(mg_base + r) * 1024 + ng] = acc[nt][r] + bv;
  }
}

// ---------------------------------------------------------------------------
// Flash attention, S^T orientation, 16 q per wave (64 q per block, 1024
// blocks = 4/CU at 33 KB LDS).  Grid (bh=64, qt=16): qt-blocks of a head
// share an XCD -> K/V L2-local.  Q fragments hoisted to registers (loop-
// invariant).  Q pre-scaled by log2(e) -> exp2 softmax, no max shift.
// Reference divides by sqrt(E)=32 AFTER softmax -> /(l*32).
// ---------------------------------------------------------------------------
__global__ __launch_bounds__(256) void attn_kernel(const __bf16* __restrict__ Q,
                                                   const __bf16* __restrict__ K,
                                                   const __bf16* __restrict__ Vt,
                                                   __bf16* __restrict__ O) {
  __shared__ __attribute__((aligned(16))) __bf16 Qs[64][64];
  __shared__ __attribute__((aligned(16))) __bf16 Ks[64][64];
  __shared__ __attribute__((aligned(16))) __bf16 Vs[64][64];
  __shared__ __attribute__((aligned(16))) __bf16 Ps[4][16][72];

  const int tid = threadIdx.x;
  const int lane = tid & 63, w = tid >> 6;
  const int l15 = lane & 15, lq = lane >> 4;
  const int lr = lane >> 3, lc = lane & 7;
  const int xs = l15 & 7;

  const int bh = blockIdx.x;  // 0..63  (same-head blocks share an XCD)
  const int qt = blockIdx.y;  // 0..15
  const __bf16* Qh = Q + (size_t)bh * 65536;
  const __bf16* Kh = K + (size_t)bh * 65536;
  const __bf16* Vh = Vt + (size_t)bh * 65536;

  // stage Q tile (64x64) once via glds, then hoist this wave's fragments
#pragma unroll
  for (int i = 0; i < 2; ++i) {
    const int row = w * 16 + i * 8 + lr;
    glds16(Qh + (size_t)(qt * 64 + row) * 64 + ((lc ^ lr) * 8), &Qs[row][lc * 8]);
  }
  __syncthreads();  // drain Q glds for all waves
  bf16x8 bqr[2];
#pragma unroll
  for (int s = 0; s < 2; ++s)
    bqr[s] = *(const bf16x8*)(&Qs[w * 16 + l15][((s * 4 + lq) ^ xs) * 8]);

  float l_run = 0.0f;
  f32x4 oacc[4] = {};

  for (int kb = 0; kb < 16; ++kb) {
    // stage K/V (prev-iter readers protected by trailing sync)
#pragma unroll
    for (int i = 0; i < 2; ++i) {
      const int row = w * 16 + i * 8 + lr;
      glds16(Kh + (size_t)kb * 4096 + (size_t)row * 64 + ((lc ^ lr) * 8), &Ks[row][lc * 8]);
      glds16(Vh + (size_t)row * 1024 + kb * 64 + ((lc ^ lr) * 8), &Vs[row][lc * 8]);
    }
    __syncthreads();

    // S^T: rows = kseq(64), cols = this wave's 16 q
    f32x4 sacc[4] = {};
#pragma unroll
    for (int s = 0; s < 2; ++s) {
#pragma unroll
      for (int mt = 0; mt < 4; ++mt) {
        bf16x8 ak = *(const bf16x8*)(&Ks[mt * 16 + l15][((s * 4 + lq) ^ xs) * 8]);
        sacc[mt] = __builtin_amdgcn_mfma_f32_16x16x32_bf16(ak, bqr[s], sacc[mt], 0, 0, 0);
      }
    }

    // softmax numerator via exp2 (per-lane q = w*16 + l15)
    float sum = 0.0f;
#pragma unroll
    for (int mt = 0; mt < 4; ++mt)
#pragma unroll
      for (int r = 0; r < 4; ++r) {
        const float e = __builtin_amdgcn_exp2f(sacc[mt][r]);
        sacc[mt][r] = e;
        sum += e;
      }
    sum += __shfl_xor(sum, 16, 64);
    sum += __shfl_xor(sum, 32, 64);
    l_run += sum;

    // P -> LDS row-major [q][k] (padded), lane writes 4 consecutive k (b64)
#pragma unroll
    for (int mt = 0; mt < 4; ++mt) {
      bf16x4 p4 = {(__bf16)sacc[mt][0], (__bf16)sacc[mt][1],
                   (__bf16)sacc[mt][2], (__bf16)sacc[mt][3]};
      *(bf16x4*)(&Ps[w][l15][mt * 16 + lq * 4]) = p4;
    }
    __threadfence_block();  // wave-private P round-trip

    // O^T += Vt · P
#pragma unroll
    for (int s = 0; s < 2; ++s) {
      bf16x8 bp = *(const bf16x8*)(&Ps[w][l15][s * 32 + lq * 8]);
#pragma unroll
      for (int mt = 0; mt < 4; ++mt) {
        bf16x8 av = *(const bf16x8*)(&Vs[mt * 16 + l15][((s * 4 + lq) ^ xs) * 8]);
        oacc[mt] = __builtin_amdgcn_mfma_f32_16x16x32_bf16(av, bp, oacc[mt], 0, 0, 0);
      }
    }
    __syncthreads();  // Ks/Vs readers done before next stage overwrites
  }

  // epilogue: O^T col=q(l15), row=d=mt*16+lq*4+r; write O[b*1024+q][h*64+d]
  const int b = bh >> 4, h = bh & 15;
  const float inv = 1.0f / (l_run * 32.0f);
  const size_t base = (size_t)(b * 1024 + qt * 64 + w * 16 + l15) * 1024 + h * 64;
#pragma unroll
  for (int mt = 0; mt < 4; ++mt) {
    bf16x4 o4 = {(__bf16)(oacc[mt][0] * inv), (__bf16)(oacc[mt][1] * inv),
                 (__bf16)(oacc[mt][2] * inv), (__bf16)(oacc[mt][3] * inv)};
    *(bf16x4*)(&O[base + mt * 16 + lq * 4]) = o4;
  }
}

// ---------------------------------------------------------------------------
extern "C" void kernel_launch(void* const* d_in, const int* in_sizes, int n_in,
                              void* d_out, int out_size, void* d_ws, size_t ws_size,
                              hipStream_t stream) {
  const float* x  = (const float*)d_in[0];
  const float* Wq = (const float*)d_in[1];
  const float* bq = (const float*)d_in[2];
  const float* Wk = (const float*)d_in[3];
  const float* bk = (const float*)d_in[4];
  const float* Wv = (const float*)d_in[5];
  const float* bv = (const float*)d_in[6];
  const float* Wo = (const float*)d_in[7];
  const float* bo = (const float*)d_in[8];
  float* out = (float*)d_out;

  const size_t SZ = (size_t)4 * 1024 * 1024;  // 4M bf16 per slot (8 MB)
  __bf16* Qw = (__bf16*)d_ws;
  __bf16* Kw = Qw + SZ;
  __bf16* Vw = Kw + SZ;
  __bf16* s3 = Vw + SZ;  // xb during QKV, then Ow
  __bf16* xb = s3;
  __bf16* Ow = s3;

  dim3 blk(256);

  if (ws_size >= (size_t)40 * 1024 * 1024) {
    __bf16* Wqb = s3 + SZ;  // 2 MB each
    __bf16* Wkb = Wqb + SZ / 4;
    __bf16* Wvb = Wkb + SZ / 4;
    __bf16* Wob = Wvb + SZ / 4;
    cvt_all<<<8192, blk, 0, stream>>>(x, Wq, Wk, Wv, Wo, xb, Wqb, Wkb, Wvb, Wob);
    gemm_qkv<true><<<dim3(1536), blk, 0, stream>>>(xb, Wqb, Wkb, Wvb,
                                                   bq, bk, bv, Qw, Kw, Vw);
    attn_kernel<<<dim3(64, 16), blk, 0, stream>>>(Qw, Kw, Vw, Ow);
    gemm_out<<<dim3(128, 8), blk, 0, stream>>>(Ow, Wob, bo, out);
  } else {
    __bf16* Wob = Kw;  // Kw dead after attention
    cvt_f32_bf16<<<4096, blk, 0, stream>>>(x, xb, 1048576);
    gemm_qkv<false><<<dim3(1536), blk, 0, stream>>>(xb, Wq, Wk, Wv,
                                                    bq, bk, bv, Qw, Kw, Vw);
    attn_kernel<<<dim3(64, 16), blk, 0, stream>>>(Qw, Kw, Vw, Ow);
    cvt_f32_bf16<<<1024, blk, 0, stream>>>(Wo, Wob, 262144);
    gemm_out<<<dim3(128, 8), blk, 0, stream>>>(Ow, Wob, bo, out);
  }
}